// Round 2
// baseline (1201.452 us; speedup 1.0000x reference)
//
#include <hip/hip_runtime.h>
#include <hip/hip_bf16.h>

#define B_ 8
#define S_ 2048
#define H_ 512
#define P_ 16
#define K_ 256
#define M_TOT (B_*S_)      // 16384
#define TILE_M 32

typedef short bf8v __attribute__((ext_vector_type(8)));   // 8 x bf16 (MFMA operand)
typedef float f4v  __attribute__((ext_vector_type(4)));   // MFMA accumulator

// ---- device-global scratch (recomputed from inputs on every call) ----
__device__ unsigned short g_hidden[M_TOT*H_];   // bf16 hidden, [token][h]
__device__ unsigned short g_w1t[P_*K_*H_];      // bf16 w1 transposed: [p][k_out][h]
__device__ unsigned short g_w2t[P_*H_*K_];      // bf16 w2 transposed: [p][h][k_in]
__device__ float g_bias1[P_*K_];                // embed@w1 + b1
__device__ float g_pooled[B_*H_];
__device__ float g_probs[B_*P_];
__device__ float g_bias2w[B_*H_];               // sum_p probs*b2
__device__ float g_partial[M_TOT*H_];           // expert-group-1 partial output

__device__ __forceinline__ unsigned short f2bf(float x){
  unsigned int u = __builtin_bit_cast(unsigned int, x);
  u += 0x7fffu + ((u >> 16) & 1u);              // round-to-nearest-even
  return (unsigned short)(u >> 16);
}

// exact GELU: 0.5*x*(1+erf(x/sqrt(2))), erf via A&S 7.1.26 (|err|<1.5e-7)
__device__ __forceinline__ float gelu_exact(float x){
  float z  = x * 0.70710678f;
  float az = fabsf(z);
  float t  = 1.0f / (1.0f + 0.3275911f * az);
  float poly = t*(0.254829592f + t*(-0.284496736f + t*(1.421413741f +
               t*(-1.453152027f + t*1.061405429f))));
  float e = __expf(-az*az);
  float erfv = 1.0f - poly*e;
  erfv = (z < 0.0f) ? -erfv : erfv;
  return 0.5f * x * (1.0f + erfv);
}

// ---------- pre-pass: pooled mean over S ----------
__global__ void pool_kernel(const float* __restrict__ hs){
  int b  = blockIdx.x >> 5;          // 8 batches
  int hg = blockIdx.x & 31;          // 32 h-groups of 16
  int hh = threadIdx.x & 15;
  int ss = threadIdx.x >> 4;         // 16 s-lanes
  int h  = hg*16 + hh;
  const float* p = hs + ((size_t)b*S_ + ss)*H_ + h;
  float acc = 0.0f;
  for (int s = ss; s < S_; s += 16) { acc += *p; p += 16*H_; }
  __shared__ float red[16][17];
  red[ss][hh] = acc;
  __syncthreads();
  if (ss == 0){
    float t = 0.0f;
    #pragma unroll
    for (int i=0;i<16;++i) t += red[i][hh];
    g_pooled[b*H_ + h] = t * (1.0f/S_);
  }
}

// ---------- pre-pass: logits, softmax, bias2w ----------
__global__ void routing_kernel(const float* __restrict__ head_w,
                               const float* __restrict__ head_b,
                               const float* __restrict__ b2){
  __shared__ float logits[B_][P_];
  __shared__ float sprob[B_][P_];
  int w = threadIdx.x >> 6, lane = threadIdx.x & 63;
  for (int i = 0; i < 16; ++i){                   // 128 (b,p) pairs / 8 waves
    int pair = w*16 + i; int b = pair >> 4; int p = pair & 15;
    float acc = 0.0f;
    for (int h = lane; h < H_; h += 64) acc += g_pooled[b*H_+h]*head_w[p*H_+h];
    for (int off=32; off; off>>=1) acc += __shfl_down(acc, off);
    if (lane==0) logits[b][p] = acc + head_b[p];
  }
  __syncthreads();
  if (threadIdx.x < B_){
    int b = threadIdx.x;
    float mx = -1e30f;
    #pragma unroll
    for (int p=0;p<P_;++p) mx = fmaxf(mx, logits[b][p]);
    float e[P_]; float s = 0.0f;
    #pragma unroll
    for (int p=0;p<P_;++p){ e[p] = __expf(logits[b][p]-mx); s += e[p]; }
    float inv = 1.0f/s;
    #pragma unroll
    for (int p=0;p<P_;++p){ float pr = e[p]*inv; g_probs[b*P_+p] = pr; sprob[b][p] = pr; }
  }
  __syncthreads();
  for (int idx = threadIdx.x; idx < B_*H_; idx += blockDim.x){
    int b = idx >> 9, h = idx & (H_-1);
    float a = 0.0f;
    #pragma unroll
    for (int p=0;p<P_;++p) a += sprob[b][p]*b2[p*H_+h];
    g_bias2w[idx] = a;
  }
}

// ---------- pre-pass: hidden fp32 -> bf16 ----------
__global__ void cvt_hidden(const float* __restrict__ x){
  size_t i = (size_t)blockIdx.x*blockDim.x + threadIdx.x;   // over M*H/4
  float4 a = ((const float4*)x)[i];
  ushort4 o; o.x=f2bf(a.x); o.y=f2bf(a.y); o.z=f2bf(a.z); o.w=f2bf(a.w);
  ((ushort4*)g_hidden)[i] = o;
}

// ---------- pre-pass: transpose+convert weights: in[p][R][C] f32 -> out[p][C][R] bf16 ----------
__global__ void transpose_cvt(const float* __restrict__ in, int R, int C, int which){
  unsigned short* out = which ? g_w2t : g_w1t;
  int nrt = R >> 5, nct = C >> 5;
  int p   = blockIdx.x / (nrt*nct);
  int rem = blockIdx.x % (nrt*nct);
  int rt = rem / nct, ct = rem % nct;
  int tx = threadIdx.x & 31, ty = threadIdx.x >> 5;    // 32 x 8
  __shared__ float t[32][33];
  const float* ip = in + (size_t)p*R*C + (size_t)(rt*32 + ty)*C + ct*32 + tx;
  #pragma unroll
  for (int k=0;k<4;++k) t[ty + 8*k][tx] = ip[(size_t)8*k*C];
  __syncthreads();
  unsigned short* op = out + (size_t)p*R*C + (size_t)(ct*32 + ty)*R + rt*32 + tx;
  #pragma unroll
  for (int k=0;k<4;++k) op[(size_t)8*k*R] = f2bf(t[tx][ty + 8*k]);
}

// ---------- pre-pass: bias1[p][k] = embed[p]@w1[p][:,k] + b1[p][k] ----------
__global__ void bias1_kernel(const float* __restrict__ embeds,
                             const float* __restrict__ w1,
                             const float* __restrict__ b1){
  int p = blockIdx.x >> 3, kg = blockIdx.x & 7;
  int ks = threadIdx.x & 31, hs = threadIdx.x >> 5;   // 32 k x 8 h-lanes
  int kk = kg*32 + ks;
  float acc = 0.0f;
  for (int h = hs; h < H_; h += 8)
    acc += embeds[p*H_ + h] * w1[((size_t)p*H_ + h)*K_ + kk];
  __shared__ float red[8][33];
  red[hs][ks] = acc; __syncthreads();
  if (hs==0){
    float t = 0.0f;
    #pragma unroll
    for (int i=0;i<8;++i) t += red[i][ks];
    g_bias1[p*K_ + kk] = t + b1[p*K_+kk];
  }
}

// ---------- main fused expert-MLP kernel ----------
// grid = 1024 blocks, 256 threads (4 waves, 2M x 2N), TILE_M = 32.
// XCD-aware mapping: xcd = bid&7 (round-robin); each XCD owns 64 contiguous
// tiles with BOTH expert groups co-located -> per-XCD L2 hot set:
// 64 tiles * 32KB hidden = 2MB + 2 experts * 0.5MB weights = 1MB < 4MB.
__global__ __launch_bounds__(256, 3) void main_kernel(float* __restrict__ out){
  __shared__ unsigned short mid[TILE_M * K_];   // 16 KiB, XOR-swizzled
  const int bid  = blockIdx.x;
  const int xcd  = bid & 7;
  const int rest = bid >> 3;
  const int grp  = rest & 1;
  const int tile = xcd*64 + (rest >> 1);        // [0, 512)
  const int tid  = threadIdx.x;
  const int w    = tid >> 6;
  const int lane = tid & 63;
  const int wm = w >> 1, wn = w & 1;
  const int l15 = lane & 15, lhi = lane >> 4;
  const int b = tile >> 6;                      // 64 tiles per batch
  const int row0 = tile*TILE_M;

  const unsigned short* Abase = g_hidden + (size_t)(row0 + wm*16 + l15)*H_ + lhi*8;

  f4v oacc[16];
  #pragma unroll
  for (int i=0;i<16;++i) oacc[i] = {0.f,0.f,0.f,0.f};

  for (int pi = 0; pi < 8; ++pi){
    const int p = grp*8 + pi;
    const float prob = g_probs[b*P_ + p];
    const unsigned short* w1p = g_w1t + (size_t)p*K_*H_;
    const unsigned short* w2p = g_w2t + (size_t)p*H_*K_;

    // ----- layer 1: mid = prob * gelu(hidden @ w1 + bias1)
    // wave (wm,wn): rows wm*16..+16, cols wn*128..+128 in 2 halves of 64
    #pragma unroll
    for (int h2 = 0; h2 < 2; ++h2){
      const int ncol0 = wn*128 + h2*64;
      const unsigned short* Bp = w1p + (size_t)(ncol0 + l15)*H_ + lhi*8;
      f4v acc[4];
      #pragma unroll
      for (int i=0;i<4;++i) acc[i] = {0.f,0.f,0.f,0.f};
      // 1-ahead register prefetch of A and B fragments
      bf8v aC = *(const bf8v*)(Abase);
      bf8v b0 = *(const bf8v*)(Bp);
      bf8v b1v = *(const bf8v*)(Bp + 16*H_);
      bf8v b2v = *(const bf8v*)(Bp + 32*H_);
      bf8v b3v = *(const bf8v*)(Bp + 48*H_);
      #pragma unroll
      for (int ks = 0; ks < 16; ++ks){
        bf8v aN, n0, n1, n2, n3;
        if (ks < 15){
          aN = *(const bf8v*)(Abase + (ks+1)*32);
          n0 = *(const bf8v*)(Bp + (ks+1)*32);
          n1 = *(const bf8v*)(Bp + 16*H_ + (ks+1)*32);
          n2 = *(const bf8v*)(Bp + 32*H_ + (ks+1)*32);
          n3 = *(const bf8v*)(Bp + 48*H_ + (ks+1)*32);
        }
        acc[0] = __builtin_amdgcn_mfma_f32_16x16x32_bf16(aC, b0,  acc[0], 0,0,0);
        acc[1] = __builtin_amdgcn_mfma_f32_16x16x32_bf16(aC, b1v, acc[1], 0,0,0);
        acc[2] = __builtin_amdgcn_mfma_f32_16x16x32_bf16(aC, b2v, acc[2], 0,0,0);
        acc[3] = __builtin_amdgcn_mfma_f32_16x16x32_bf16(aC, b3v, acc[3], 0,0,0);
        if (ks < 15){ aC = aN; b0 = n0; b1v = n1; b2v = n2; b3v = n3; }
      }
      #pragma unroll
      for (int nt=0; nt<4; ++nt){
        const int col  = ncol0 + nt*16 + l15;
        const float bias = g_bias1[p*K_ + col];
        #pragma unroll
        for (int j=0;j<4;++j){
          const int rr = wm*16 + lhi*4 + j;
          float v = acc[nt][j] + bias;
          v = gelu_exact(v) * prob;
          mid[(rr*K_ + col) ^ ((rr&7)<<3)] = f2bf(v);
        }
      }
    }
    __syncthreads();

    // ----- layer 2: oacc += mid @ w2
    // wave (wm,wn): rows wm*16..+16, cols wn*256..+256 in 4 quarters of 64
    {
      const int r0 = wm*16 + l15;
      const int abase = r0*K_;
      const int axor = (r0&7)<<3;
      #pragma unroll
      for (int q=0; q<4; ++q){
        const int ncol0 = wn*256 + q*64;
        const unsigned short* Bp2 = w2p + (size_t)(ncol0 + l15)*K_ + lhi*8;
        bf8v aC = *(const bf8v*)&mid[(abase + lhi*8) ^ axor];
        bf8v b0 = *(const bf8v*)(Bp2);
        bf8v b1v = *(const bf8v*)(Bp2 + 16*K_);
        bf8v b2v = *(const bf8v*)(Bp2 + 32*K_);
        bf8v b3v = *(const bf8v*)(Bp2 + 48*K_);
        #pragma unroll
        for (int ks=0; ks<8; ++ks){
          bf8v aN, n0, n1, n2, n3;
          if (ks < 7){
            aN = *(const bf8v*)&mid[(abase + (ks+1)*32 + lhi*8) ^ axor];
            n0 = *(const bf8v*)(Bp2 + (ks+1)*32);
            n1 = *(const bf8v*)(Bp2 + 16*K_ + (ks+1)*32);
            n2 = *(const bf8v*)(Bp2 + 32*K_ + (ks+1)*32);
            n3 = *(const bf8v*)(Bp2 + 48*K_ + (ks+1)*32);
          }
          oacc[q*4+0] = __builtin_amdgcn_mfma_f32_16x16x32_bf16(aC, b0,  oacc[q*4+0], 0,0,0);
          oacc[q*4+1] = __builtin_amdgcn_mfma_f32_16x16x32_bf16(aC, b1v, oacc[q*4+1], 0,0,0);
          oacc[q*4+2] = __builtin_amdgcn_mfma_f32_16x16x32_bf16(aC, b2v, oacc[q*4+2], 0,0,0);
          oacc[q*4+3] = __builtin_amdgcn_mfma_f32_16x16x32_bf16(aC, b3v, oacc[q*4+3], 0,0,0);
          if (ks < 7){ aC = aN; b0 = n0; b1v = n1; b2v = n2; b3v = n3; }
        }
      }
    }
    __syncthreads();
  }

  float* outp = grp ? g_partial : out;
  #pragma unroll
  for (int q=0; q<4; ++q){
    #pragma unroll
    for (int nt=0; nt<4; ++nt){
      const int col = wn*256 + q*64 + nt*16 + l15;
      const float extra = grp ? 0.0f : g_bias2w[b*H_ + col];
      #pragma unroll
      for (int j=0;j<4;++j){
        const int rr = row0 + wm*16 + lhi*4 + j;
        outp[(size_t)rr*H_ + col] = oacc[q*4+nt][j] + extra;
      }
    }
  }
}

// ---------- final: out += partial ----------
__global__ void sum_kernel(float* __restrict__ out){
  size_t i = (size_t)blockIdx.x*blockDim.x + threadIdx.x;   // over M*H/4
  float4 a = ((const float4*)out)[i];
  const float4 c = ((const float4*)g_partial)[i];
  a.x += c.x; a.y += c.y; a.z += c.z; a.w += c.w;
  ((float4*)out)[i] = a;
}

extern "C" void kernel_launch(void* const* d_in, const int* in_sizes, int n_in,
                              void* d_out, int out_size, void* d_ws, size_t ws_size,
                              hipStream_t stream){
  const float* hidden = (const float*)d_in[0];
  const float* head_w = (const float*)d_in[1];
  const float* head_b = (const float*)d_in[2];
  const float* embeds = (const float*)d_in[3];
  const float* w1     = (const float*)d_in[4];
  const float* b1     = (const float*)d_in[5];
  const float* w2     = (const float*)d_in[6];
  const float* b2     = (const float*)d_in[7];
  float* out = (float*)d_out;
  (void)in_sizes; (void)n_in; (void)out_size; (void)d_ws; (void)ws_size;

  pool_kernel   <<<B_*32, 256, 0, stream>>>(hidden);
  routing_kernel<<<1, 512, 0, stream>>>(head_w, head_b, b2);
  cvt_hidden    <<<(M_TOT*H_/4)/256, 256, 0, stream>>>(hidden);
  transpose_cvt <<<P_*(H_/32)*(K_/32), 256, 0, stream>>>(w1, H_, K_, 0);
  transpose_cvt <<<P_*(K_/32)*(H_/32), 256, 0, stream>>>(w2, K_, H_, 1);
  bias1_kernel  <<<P_*8, 256, 0, stream>>>(embeds, w1, b1);
  main_kernel   <<<8*64*2, 256, 0, stream>>>(out);
  sum_kernel    <<<(M_TOT*H_/4)/256, 256, 0, stream>>>(out);
}

// Round 3
// 365.251 us; speedup vs baseline: 3.2894x; 3.2894x over previous
//
#include <hip/hip_runtime.h>
#include <hip/hip_bf16.h>
#include <stdint.h>

#define B_ 8
#define S_ 2048
#define H_ 512
#define P_ 16
#define K_ 256
#define M_TOT (B_*S_)      // 16384
#define KCAT (P_*K_)       // 4096

typedef short bf8v __attribute__((ext_vector_type(8)));   // 8 x bf16 (MFMA operand)
typedef float f4v  __attribute__((ext_vector_type(4)));   // MFMA accumulator

// ---- device-global scratch (recomputed from inputs on every call) ----
__device__ __align__(16) unsigned short g_hidden[M_TOT*H_];        // bf16 [m][h]
__device__ __align__(16) unsigned short g_w1t[P_*K_*H_];           // bf16 [p][k_out][h]
__device__ __align__(16) unsigned short g_w2cat[H_*KCAT];          // bf16 [h][p*256+k_in]
__device__ __align__(16) unsigned short g_mid[(size_t)M_TOT*KCAT]; // bf16 [m][p*256+k]
__device__ float g_bias1[P_*K_];
__device__ float g_probs[B_*P_];
__device__ float g_bias2w[B_*H_];

__device__ __forceinline__ unsigned short f2bf(float x){
  unsigned int u = __builtin_bit_cast(unsigned int, x);
  u += 0x7fffu + ((u >> 16) & 1u);              // round-to-nearest-even
  return (unsigned short)(u >> 16);
}

// exact GELU: 0.5*x*(1+erf(x/sqrt(2))), erf via A&S 7.1.26 (|err|<1.5e-7)
__device__ __forceinline__ float gelu_exact(float x){
  float z  = x * 0.70710678f;
  float az = fabsf(z);
  float t  = 1.0f / (1.0f + 0.3275911f * az);
  float poly = t*(0.254829592f + t*(-0.284496736f + t*(1.421413741f +
               t*(-1.453152027f + t*1.061405429f))));
  float e = __expf(-az*az);
  float erfv = 1.0f - poly*e;
  erfv = (z < 0.0f) ? -erfv : erfv;
  return 0.5f * x * (1.0f + erfv);
}

__device__ __forceinline__ void gll16(const unsigned short* src, unsigned short* lds){
  __builtin_amdgcn_global_load_lds(
      (const __attribute__((address_space(1))) unsigned int*)src,
      (__attribute__((address_space(3))) unsigned int*)lds,
      16, 0, 0);
}

// ---------- pre-pass: hidden fp32 -> bf16, fused with pooled-sum ----------
// block: 64 rows x 512 h; 256 thr: tx = h4-chunk (0..127), ty = row parity
__global__ void cvt_pool(const float* __restrict__ hs, float* __restrict__ pooled){
  const int row0 = blockIdx.x * 64;
  const int b = row0 >> 11;
  const int tx = threadIdx.x & 127, ty = threadIdx.x >> 7;
  const float4* src = (const float4*)(hs + (size_t)row0*H_) + tx;
  ushort4* dst = (ushort4*)g_hidden + (size_t)row0*(H_/4) + tx;
  float4 s = {0.f,0.f,0.f,0.f};
  for (int r = ty; r < 64; r += 2){
    float4 v = src[(size_t)r*128];
    s.x += v.x; s.y += v.y; s.z += v.z; s.w += v.w;
    ushort4 o = {f2bf(v.x), f2bf(v.y), f2bf(v.z), f2bf(v.w)};
    dst[(size_t)r*128] = o;
  }
  __shared__ float4 red[256];
  red[threadIdx.x] = s;
  __syncthreads();
  if (ty == 0){
    float4 a = red[threadIdx.x], c = red[threadIdx.x + 128];
    atomicAdd(&pooled[b*H_ + tx*4 + 0], a.x + c.x);
    atomicAdd(&pooled[b*H_ + tx*4 + 1], a.y + c.y);
    atomicAdd(&pooled[b*H_ + tx*4 + 2], a.z + c.z);
    atomicAdd(&pooled[b*H_ + tx*4 + 3], a.w + c.w);
  }
}

// ---------- pre-pass: logits, softmax, bias2w ----------
__global__ void routing_kernel(const float* __restrict__ pooled,
                               const float* __restrict__ head_w,
                               const float* __restrict__ head_b,
                               const float* __restrict__ b2){
  __shared__ float logits[B_][P_];
  __shared__ float sprob[B_][P_];
  int w = threadIdx.x >> 6, lane = threadIdx.x & 63;
  for (int i = 0; i < 16; ++i){                   // 128 (b,p) pairs / 8 waves
    int pair = w*16 + i; int b = pair >> 4; int p = pair & 15;
    float acc = 0.0f;
    for (int h = lane; h < H_; h += 64) acc += pooled[b*H_+h]*head_w[p*H_+h];
    for (int off=32; off; off>>=1) acc += __shfl_down(acc, off);
    if (lane==0) logits[b][p] = acc * (1.0f/S_) + head_b[p];
  }
  __syncthreads();
  if (threadIdx.x < B_){
    int b = threadIdx.x;
    float mx = -1e30f;
    #pragma unroll
    for (int p=0;p<P_;++p) mx = fmaxf(mx, logits[b][p]);
    float e[P_]; float s = 0.0f;
    #pragma unroll
    for (int p=0;p<P_;++p){ e[p] = __expf(logits[b][p]-mx); s += e[p]; }
    float inv = 1.0f/s;
    #pragma unroll
    for (int p=0;p<P_;++p){ float pr = e[p]*inv; g_probs[b*P_+p] = pr; sprob[b][p] = pr; }
  }
  __syncthreads();
  for (int idx = threadIdx.x; idx < B_*H_; idx += blockDim.x){
    int b = idx >> 9, h = idx & (H_-1);
    float a = 0.0f;
    #pragma unroll
    for (int p=0;p<P_;++p) a += sprob[b][p]*b2[p*H_+h];
    g_bias2w[idx] = a;
  }
}

// ---------- pre-pass: transpose+convert weights ----------
// which==0: w1 in[p][512 h][256 k] -> g_w1t[p][k][h]
// which==1: w2 in[p][256 k][512 h] -> g_w2cat[h][p*256+k]
__global__ void transpose_cvt(const float* __restrict__ in, int R, int C, int which){
  int nrt = R >> 5, nct = C >> 5;
  int p   = blockIdx.x / (nrt*nct);
  int rem = blockIdx.x % (nrt*nct);
  int rt = rem / nct, ct = rem % nct;
  int tx = threadIdx.x & 31, ty = threadIdx.x >> 5;    // 32 x 8
  __shared__ float t[32][33];
  const float* ip = in + (size_t)p*R*C + (size_t)(rt*32 + ty)*C + ct*32 + tx;
  #pragma unroll
  for (int k=0;k<4;++k) t[ty + 8*k][tx] = ip[(size_t)8*k*C];
  __syncthreads();
  if (which == 0){
    unsigned short* op = g_w1t + (size_t)p*R*C + (size_t)(ct*32 + ty)*R + rt*32 + tx;
    #pragma unroll
    for (int k=0;k<4;++k) op[(size_t)8*k*R] = f2bf(t[tx][ty + 8*k]);
  } else {
    // out row = h (C-idx), col = p*256 + k (R-idx)
    unsigned short* op = g_w2cat + (size_t)(ct*32 + ty)*KCAT + p*K_ + rt*32 + tx;
    #pragma unroll
    for (int k=0;k<4;++k) op[(size_t)8*k*KCAT] = f2bf(t[tx][ty + 8*k]);
  }
}

// ---------- pre-pass: bias1[p][k] = embed[p]@w1[p][:,k] + b1[p][k] ----------
__global__ void bias1_kernel(const float* __restrict__ embeds,
                             const float* __restrict__ w1,
                             const float* __restrict__ b1){
  int p = blockIdx.x >> 3, kg = blockIdx.x & 7;
  int ks = threadIdx.x & 31, hs = threadIdx.x >> 5;   // 32 k x 8 h-lanes
  int kk = kg*32 + ks;
  float acc = 0.0f;
  for (int h = hs; h < H_; h += 8)
    acc += embeds[p*H_ + h] * w1[((size_t)p*H_ + h)*K_ + kk];
  __shared__ float red[8][33];
  red[hs][ks] = acc; __syncthreads();
  if (hs==0){
    float t = 0.0f;
    #pragma unroll
    for (int i=0;i<8;++i) t += red[i][ks];
    g_bias1[p*K_ + kk] = t + b1[p*K_+kk];
  }
}

// ================= main GEMM template =================
// BM=64, BN=256, BK=64. 256 thr = 4 waves (2M x 2N), wave-tile 32x128, acc[2][8].
// LDS tiles stored [row][64k] bf16 (128B rows), XOR-swizzled: byte ^= (row&7)<<4.
// global_load_lds: linear LDS dest, inverse-swizzled per-lane global source.

__device__ __forceinline__ void stage_tile(unsigned short* AbBuf, unsigned short* BbBuf,
    const unsigned short* gA, int sA, const unsigned short* gB, int sB,
    int koff, int w, int lane){
  const int l8 = lane >> 3, l7 = lane & 7;
  #pragma unroll
  for (int i=0;i<2;++i){                 // A: 64 rows, wave w -> rows 16w..16w+15
    int row = w*16 + i*8 + l8;
    int kunit = l7 ^ (row & 7);
    gll16(gA + (size_t)row*sA + koff + kunit*8, AbBuf + w*1024 + i*512 + lane*8);
  }
  #pragma unroll
  for (int i=0;i<8;++i){                 // B: 256 rows, wave w -> rows 64w..64w+63
    int row = w*64 + i*8 + l8;
    int kunit = l7 ^ (row & 7);
    gll16(gB + (size_t)row*sB + koff + kunit*8, BbBuf + w*4096 + i*512 + lane*8);
  }
}

__device__ __forceinline__ void kcompute(const unsigned short* Ab, const unsigned short* Bb,
    int wm, int wn, int l15, int lhi, f4v acc[2][8]){
  #pragma unroll
  for (int ksub=0; ksub<2; ++ksub){
    const int kb = ksub*64 + lhi*16;
    bf8v aF[2], bF[8];
    #pragma unroll
    for (int mt=0; mt<2; ++mt){
      int row = wm*32 + mt*16 + l15;
      aF[mt] = *(const bf8v*)((const char*)Ab + row*128 + (kb ^ ((row&7)<<4)));
    }
    #pragma unroll
    for (int nt=0; nt<8; ++nt){
      int row = wn*128 + nt*16 + l15;
      bF[nt] = *(const bf8v*)((const char*)Bb + row*128 + (kb ^ ((row&7)<<4)));
    }
    #pragma unroll
    for (int mt=0; mt<2; ++mt)
      #pragma unroll
      for (int nt=0; nt<8; ++nt)
        acc[mt][nt] = __builtin_amdgcn_mfma_f32_16x16x32_bf16(aF[mt], bF[nt], acc[mt][nt], 0,0,0);
  }
}

// ---------- layer 1: mid = prob * gelu(hidden @ w1t^T + bias1), bf16 ----------
// grid = P_ * 256 m-tiles = 4096 blocks
__global__ __launch_bounds__(256, 2) void l1_kernel(){
  __shared__ __align__(16) unsigned short Ab[2][64*64];
  __shared__ __align__(16) unsigned short Bb[2][256*64];
  const int p = blockIdx.x >> 8;
  const int row0 = (blockIdx.x & 255) * 64;
  const int b = row0 >> 11;
  const int tid = threadIdx.x, w = tid >> 6, lane = tid & 63;
  const int wm = w >> 1, wn = w & 1, l15 = lane & 15, lhi = lane >> 4;
  const unsigned short* gA = g_hidden + (size_t)row0 * H_;
  const unsigned short* gB = g_w1t + (size_t)p * K_ * H_;

  f4v acc[2][8];
  #pragma unroll
  for (int i=0;i<2;++i)
    #pragma unroll
    for (int j=0;j<8;++j) acc[i][j] = {0.f,0.f,0.f,0.f};

  stage_tile(Ab[0], Bb[0], gA, H_, gB, H_, 0, w, lane);
  __syncthreads();
  int cur = 0;
  for (int kt = 0; kt < 8; ++kt){
    if (kt < 7) stage_tile(Ab[cur^1], Bb[cur^1], gA, H_, gB, H_, (kt+1)*64, w, lane);
    kcompute(Ab[cur], Bb[cur], wm, wn, l15, lhi, acc);
    __syncthreads();
    cur ^= 1;
  }

  const float prob = g_probs[b*P_ + p];
  #pragma unroll
  for (int nt=0; nt<8; ++nt){
    const int col = wn*128 + nt*16 + l15;
    const float bias = g_bias1[p*K_ + col];
    #pragma unroll
    for (int mt=0; mt<2; ++mt){
      #pragma unroll
      for (int j=0;j<4;++j){
        const int row = wm*32 + mt*16 + lhi*4 + j;
        float v = acc[mt][nt][j] + bias;
        g_mid[(size_t)(row0+row)*KCAT + p*K_ + col] = f2bf(gelu_exact(v)*prob);
      }
    }
  }
}

// ---------- layer 2: out[m][h] = mid[m][:] @ w2cat[h][:] + bias2w, fp32 ----------
// single GEMM M=16384, N=512, K=4096; grid = 256 m-tiles * 2 n-tiles = 512 blocks
__global__ __launch_bounds__(256, 2) void l2_kernel(float* __restrict__ out){
  __shared__ __align__(16) unsigned short Ab[2][64*64];
  __shared__ __align__(16) unsigned short Bb[2][256*64];
  const int row0 = (blockIdx.x >> 1) * 64;
  const int n0 = (blockIdx.x & 1) * 256;
  const int b = row0 >> 11;
  const int tid = threadIdx.x, w = tid >> 6, lane = tid & 63;
  const int wm = w >> 1, wn = w & 1, l15 = lane & 15, lhi = lane >> 4;
  const unsigned short* gA = g_mid + (size_t)row0 * KCAT;
  const unsigned short* gB = g_w2cat + (size_t)n0 * KCAT;

  f4v acc[2][8];
  #pragma unroll
  for (int i=0;i<2;++i)
    #pragma unroll
    for (int j=0;j<8;++j) acc[i][j] = {0.f,0.f,0.f,0.f};

  stage_tile(Ab[0], Bb[0], gA, KCAT, gB, KCAT, 0, w, lane);
  __syncthreads();
  int cur = 0;
  for (int kt = 0; kt < 64; ++kt){
    if (kt < 63) stage_tile(Ab[cur^1], Bb[cur^1], gA, KCAT, gB, KCAT, (kt+1)*64, w, lane);
    kcompute(Ab[cur], Bb[cur], wm, wn, l15, lhi, acc);
    __syncthreads();
    cur ^= 1;
  }

  #pragma unroll
  for (int nt=0; nt<8; ++nt){
    const int col = wn*128 + nt*16 + l15;
    const float extra = g_bias2w[b*H_ + n0 + col];
    #pragma unroll
    for (int mt=0; mt<2; ++mt){
      #pragma unroll
      for (int j=0;j<4;++j){
        const int row = wm*32 + mt*16 + lhi*4 + j;
        out[(size_t)(row0+row)*H_ + n0 + col] = acc[mt][nt][j] + extra;
      }
    }
  }
}

extern "C" void kernel_launch(void* const* d_in, const int* in_sizes, int n_in,
                              void* d_out, int out_size, void* d_ws, size_t ws_size,
                              hipStream_t stream){
  const float* hidden = (const float*)d_in[0];
  const float* head_w = (const float*)d_in[1];
  const float* head_b = (const float*)d_in[2];
  const float* embeds = (const float*)d_in[3];
  const float* w1     = (const float*)d_in[4];
  const float* b1     = (const float*)d_in[5];
  const float* w2     = (const float*)d_in[6];
  const float* b2     = (const float*)d_in[7];
  float* out = (float*)d_out;
  float* pooled = (float*)d_ws;   // B_*H_ floats, zeroed below
  (void)in_sizes; (void)n_in; (void)out_size; (void)ws_size;

  hipMemsetAsync(pooled, 0, B_*H_*sizeof(float), stream);
  cvt_pool      <<<M_TOT/64, 256, 0, stream>>>(hidden, pooled);
  routing_kernel<<<1, 512, 0, stream>>>(pooled, head_w, head_b, b2);
  transpose_cvt <<<P_*(H_/32)*(K_/32), 256, 0, stream>>>(w1, H_, K_, 0);
  transpose_cvt <<<P_*(K_/32)*(H_/32), 256, 0, stream>>>(w2, K_, H_, 1);
  bias1_kernel  <<<P_*8, 256, 0, stream>>>(embeds, w1, b1);
  l1_kernel     <<<P_*256, 256, 0, stream>>>();
  l2_kernel     <<<512, 256, 0, stream>>>(out);
}

// Round 4
// 338.841 us; speedup vs baseline: 3.5458x; 1.0779x over previous
//
#include <hip/hip_runtime.h>
#include <hip/hip_bf16.h>
#include <stdint.h>

#define B_ 8
#define S_ 2048
#define H_ 512
#define P_ 16
#define K_ 256
#define M_TOT (B_*S_)      // 16384
#define KCAT (P_*K_)       // 4096

typedef short bf8v __attribute__((ext_vector_type(8)));   // 8 x bf16 (MFMA operand)
typedef float f4v  __attribute__((ext_vector_type(4)));   // MFMA accumulator

// ---- device-global scratch (recomputed from inputs on every call) ----
__device__ __align__(16) unsigned short g_hidden[M_TOT*H_];        // bf16 [m][h]
__device__ __align__(16) unsigned short g_w1t[P_*K_*H_];           // bf16 [p][k_out][h]
__device__ __align__(16) unsigned short g_w2cat[H_*KCAT];          // bf16 [h][p*256+k_in]
__device__ __align__(16) unsigned short g_mid[(size_t)M_TOT*KCAT]; // bf16 [m][p*256+k]
__device__ float g_bias1[P_*K_];
__device__ float g_probs[B_*P_];
__device__ float g_bias2w[B_*H_];

__device__ __forceinline__ unsigned short f2bf(float x){
  unsigned int u = __builtin_bit_cast(unsigned int, x);
  u += 0x7fffu + ((u >> 16) & 1u);              // round-to-nearest-even
  return (unsigned short)(u >> 16);
}

// exact GELU: 0.5*x*(1+erf(x/sqrt(2))), erf via A&S 7.1.26 (|err|<1.5e-7)
__device__ __forceinline__ float gelu_exact(float x){
  float z  = x * 0.70710678f;
  float az = fabsf(z);
  float t  = 1.0f / (1.0f + 0.3275911f * az);
  float poly = t*(0.254829592f + t*(-0.284496736f + t*(1.421413741f +
               t*(-1.453152027f + t*1.061405429f))));
  float e = __expf(-az*az);
  float erfv = 1.0f - poly*e;
  erfv = (z < 0.0f) ? -erfv : erfv;
  return 0.5f * x * (1.0f + erfv);
}

__device__ __forceinline__ void gll16(const unsigned short* src, unsigned short* lds){
  __builtin_amdgcn_global_load_lds(
      (const __attribute__((address_space(1))) unsigned int*)src,
      (__attribute__((address_space(3))) unsigned int*)lds,
      16, 0, 0);
}

// ---------- pre-pass: hidden fp32 -> bf16, fused with pooled-sum ----------
__global__ void cvt_pool(const float* __restrict__ hs, float* __restrict__ pooled){
  const int row0 = blockIdx.x * 64;
  const int b = row0 >> 11;
  const int tx = threadIdx.x & 127, ty = threadIdx.x >> 7;
  const float4* src = (const float4*)(hs + (size_t)row0*H_) + tx;
  ushort4* dst = (ushort4*)g_hidden + (size_t)row0*(H_/4) + tx;
  float4 s = {0.f,0.f,0.f,0.f};
  for (int r = ty; r < 64; r += 2){
    float4 v = src[(size_t)r*128];
    s.x += v.x; s.y += v.y; s.z += v.z; s.w += v.w;
    ushort4 o = {f2bf(v.x), f2bf(v.y), f2bf(v.z), f2bf(v.w)};
    dst[(size_t)r*128] = o;
  }
  __shared__ float4 red[256];
  red[threadIdx.x] = s;
  __syncthreads();
  if (ty == 0){
    float4 a = red[threadIdx.x], c = red[threadIdx.x + 128];
    atomicAdd(&pooled[b*H_ + tx*4 + 0], a.x + c.x);
    atomicAdd(&pooled[b*H_ + tx*4 + 1], a.y + c.y);
    atomicAdd(&pooled[b*H_ + tx*4 + 2], a.z + c.z);
    atomicAdd(&pooled[b*H_ + tx*4 + 3], a.w + c.w);
  }
}

// ---------- pre-pass: logits, softmax, bias2w ----------
__global__ void routing_kernel(const float* __restrict__ pooled,
                               const float* __restrict__ head_w,
                               const float* __restrict__ head_b,
                               const float* __restrict__ b2){
  __shared__ float logits[B_][P_];
  __shared__ float sprob[B_][P_];
  int w = threadIdx.x >> 6, lane = threadIdx.x & 63;
  for (int i = 0; i < 16; ++i){
    int pair = w*16 + i; int b = pair >> 4; int p = pair & 15;
    float acc = 0.0f;
    for (int h = lane; h < H_; h += 64) acc += pooled[b*H_+h]*head_w[p*H_+h];
    for (int off=32; off; off>>=1) acc += __shfl_down(acc, off);
    if (lane==0) logits[b][p] = acc * (1.0f/S_) + head_b[p];
  }
  __syncthreads();
  if (threadIdx.x < B_){
    int b = threadIdx.x;
    float mx = -1e30f;
    #pragma unroll
    for (int p=0;p<P_;++p) mx = fmaxf(mx, logits[b][p]);
    float e[P_]; float s = 0.0f;
    #pragma unroll
    for (int p=0;p<P_;++p){ e[p] = __expf(logits[b][p]-mx); s += e[p]; }
    float inv = 1.0f/s;
    #pragma unroll
    for (int p=0;p<P_;++p){ float pr = e[p]*inv; g_probs[b*P_+p] = pr; sprob[b][p] = pr; }
  }
  __syncthreads();
  for (int idx = threadIdx.x; idx < B_*H_; idx += blockDim.x){
    int b = idx >> 9, h = idx & (H_-1);
    float a = 0.0f;
    #pragma unroll
    for (int p=0;p<P_;++p) a += sprob[b][p]*b2[p*H_+h];
    g_bias2w[idx] = a;
  }
}

// ---------- pre-pass: transpose+convert weights ----------
__global__ void transpose_cvt(const float* __restrict__ in, int R, int C, int which){
  int nrt = R >> 5, nct = C >> 5;
  int p   = blockIdx.x / (nrt*nct);
  int rem = blockIdx.x % (nrt*nct);
  int rt = rem / nct, ct = rem % nct;
  int tx = threadIdx.x & 31, ty = threadIdx.x >> 5;    // 32 x 8
  __shared__ float t[32][33];
  const float* ip = in + (size_t)p*R*C + (size_t)(rt*32 + ty)*C + ct*32 + tx;
  #pragma unroll
  for (int k=0;k<4;++k) t[ty + 8*k][tx] = ip[(size_t)8*k*C];
  __syncthreads();
  if (which == 0){
    unsigned short* op = g_w1t + (size_t)p*R*C + (size_t)(ct*32 + ty)*R + rt*32 + tx;
    #pragma unroll
    for (int k=0;k<4;++k) op[(size_t)8*k*R] = f2bf(t[tx][ty + 8*k]);
  } else {
    unsigned short* op = g_w2cat + (size_t)(ct*32 + ty)*KCAT + p*K_ + rt*32 + tx;
    #pragma unroll
    for (int k=0;k<4;++k) op[(size_t)8*k*KCAT] = f2bf(t[tx][ty + 8*k]);
  }
}

// ---------- pre-pass: bias1[p][k] = embed[p]@w1[p][:,k] + b1[p][k] ----------
__global__ void bias1_kernel(const float* __restrict__ embeds,
                             const float* __restrict__ w1,
                             const float* __restrict__ b1){
  int p = blockIdx.x >> 3, kg = blockIdx.x & 7;
  int ks = threadIdx.x & 31, hs = threadIdx.x >> 5;
  int kk = kg*32 + ks;
  float acc = 0.0f;
  for (int h = hs; h < H_; h += 8)
    acc += embeds[p*H_ + h] * w1[((size_t)p*H_ + h)*K_ + kk];
  __shared__ float red[8][33];
  red[hs][ks] = acc; __syncthreads();
  if (hs==0){
    float t = 0.0f;
    #pragma unroll
    for (int i=0;i<8;++i) t += red[i][ks];
    g_bias1[p*K_ + kk] = t + b1[p*K_+kk];
  }
}

// ================= main GEMM template =================
// BM=64, BN=256, BK=64. 256 thr = 4 waves (2M x 2N), wave-tile 32x128, acc[2][8].
// LDS tiles [row][64k] bf16 (128B rows), XOR-swizzled: byte ^= (row&7)<<4.
// Counted-vmcnt 2-phase: next-tile global_load_lds stays in flight across the
// barrier; s_waitcnt vmcnt(10) retires only the current tile's 10 loads.

__device__ __forceinline__ void stage_tile(unsigned short* AbBuf, unsigned short* BbBuf,
    const unsigned short* gA, int sA, const unsigned short* gB, int sB,
    int koff, int w, int lane){
  const int l8 = lane >> 3, l7 = lane & 7;
  #pragma unroll
  for (int i=0;i<2;++i){                 // A: 64 rows
    int row = w*16 + i*8 + l8;
    int kunit = l7 ^ (row & 7);
    gll16(gA + (size_t)row*sA + koff + kunit*8, AbBuf + w*1024 + i*512 + lane*8);
  }
  #pragma unroll
  for (int i=0;i<8;++i){                 // B: 256 rows
    int row = w*64 + i*8 + l8;
    int kunit = l7 ^ (row & 7);
    gll16(gB + (size_t)row*sB + koff + kunit*8, BbBuf + w*4096 + i*512 + lane*8);
  }
}

__device__ __forceinline__ void kcompute(const unsigned short* Ab, const unsigned short* Bb,
    int wm, int wn, int l15, int lhi, f4v acc[2][8]){
  #pragma unroll
  for (int ksub=0; ksub<2; ++ksub){
    const int kb = ksub*64 + lhi*16;
    bf8v aF[2], bF[8];
    #pragma unroll
    for (int mt=0; mt<2; ++mt){
      int row = wm*32 + mt*16 + l15;
      aF[mt] = *(const bf8v*)((const char*)Ab + row*128 + (kb ^ ((row&7)<<4)));
    }
    #pragma unroll
    for (int nt=0; nt<8; ++nt){
      int row = wn*128 + nt*16 + l15;
      bF[nt] = *(const bf8v*)((const char*)Bb + row*128 + (kb ^ ((row&7)<<4)));
    }
    __builtin_amdgcn_s_setprio(1);
    #pragma unroll
    for (int mt=0; mt<2; ++mt)
      #pragma unroll
      for (int nt=0; nt<8; ++nt)
        acc[mt][nt] = __builtin_amdgcn_mfma_f32_16x16x32_bf16(aF[mt], bF[nt], acc[mt][nt], 0,0,0);
    __builtin_amdgcn_s_setprio(0);
  }
}

// ---------- layer 1: mid = prob * gelu(hidden @ w1t^T + bias1), bf16 ----------
__global__ __launch_bounds__(256, 2) void l1_kernel(){
  __shared__ __align__(16) unsigned short Ab[2][64*64];
  __shared__ __align__(16) unsigned short Bb[2][256*64];
  const int lb = (blockIdx.x & 7)*512 + (blockIdx.x >> 3);   // XCD-chunked
  const int p = lb >> 8;
  const int row0 = (lb & 255) * 64;
  const int b = row0 >> 11;
  const int tid = threadIdx.x, w = tid >> 6, lane = tid & 63;
  const int wm = w >> 1, wn = w & 1, l15 = lane & 15, lhi = lane >> 4;
  const unsigned short* gA = g_hidden + (size_t)row0 * H_;
  const unsigned short* gB = g_w1t + (size_t)p * K_ * H_;

  f4v acc[2][8];
  #pragma unroll
  for (int i=0;i<2;++i)
    #pragma unroll
    for (int j=0;j<8;++j) acc[i][j] = {0.f,0.f,0.f,0.f};

  stage_tile(Ab[0], Bb[0], gA, H_, gB, H_, 0, w, lane);
  int cur = 0;
  for (int kt = 0; kt < 8; ++kt){
    if (kt < 7){
      stage_tile(Ab[cur^1], Bb[cur^1], gA, H_, gB, H_, (kt+1)*64, w, lane);
      asm volatile("s_waitcnt vmcnt(10)" ::: "memory");
    } else {
      asm volatile("s_waitcnt vmcnt(0)" ::: "memory");
    }
    __builtin_amdgcn_s_barrier();
    kcompute(Ab[cur], Bb[cur], wm, wn, l15, lhi, acc);
    __builtin_amdgcn_s_barrier();
    cur ^= 1;
  }

  // epilogue: gelu -> bf16 -> swizzled LDS tile -> coalesced 16B stores
  unsigned short* mlds = &Bb[0][0];              // 64*256 = 16384 shorts
  const float prob = g_probs[b*P_ + p];
  #pragma unroll
  for (int nt=0; nt<8; ++nt){
    const int col = wn*128 + nt*16 + l15;
    const float bias = g_bias1[p*K_ + col];
    #pragma unroll
    for (int mt=0; mt<2; ++mt){
      #pragma unroll
      for (int j=0;j<4;++j){
        const int row = wm*32 + mt*16 + lhi*4 + j;
        float v = acc[mt][nt][j] + bias;
        mlds[(row*256 + col) ^ ((row&7)<<3)] = f2bf(gelu_exact(v)*prob);
      }
    }
  }
  __syncthreads();
  const int c8 = tid & 31, rr = tid >> 5;
  #pragma unroll
  for (int pass=0; pass<8; ++pass){
    const int r = pass*8 + rr;
    bf8v vv = *(const bf8v*)&mlds[(r*256 + c8*8) ^ ((r&7)<<3)];
    *(bf8v*)&g_mid[(size_t)(row0+r)*KCAT + p*K_ + c8*8] = vv;
  }
}

// ---------- layer 2: out = mid @ w2cat^T + bias2w, fp32 ----------
__global__ __launch_bounds__(256, 2) void l2_kernel(float* __restrict__ out){
  __shared__ __align__(16) unsigned short Ab[2][64*64];
  __shared__ __align__(16) unsigned short Bb[2][256*64];
  const int lb = (blockIdx.x & 7)*64 + (blockIdx.x >> 3);    // XCD-chunked
  const int n0 = (lb >> 8) * 256;
  const int row0 = (lb & 255) * 64;
  const int b = row0 >> 11;
  const int tid = threadIdx.x, w = tid >> 6, lane = tid & 63;
  const int wm = w >> 1, wn = w & 1, l15 = lane & 15, lhi = lane >> 4;
  const unsigned short* gA = g_mid + (size_t)row0 * KCAT;
  const unsigned short* gB = g_w2cat + (size_t)n0 * KCAT;

  f4v acc[2][8];
  #pragma unroll
  for (int i=0;i<2;++i)
    #pragma unroll
    for (int j=0;j<8;++j) acc[i][j] = {0.f,0.f,0.f,0.f};

  stage_tile(Ab[0], Bb[0], gA, KCAT, gB, KCAT, 0, w, lane);
  int cur = 0;
  for (int kt = 0; kt < 64; ++kt){
    if (kt < 63){
      stage_tile(Ab[cur^1], Bb[cur^1], gA, KCAT, gB, KCAT, (kt+1)*64, w, lane);
      asm volatile("s_waitcnt vmcnt(10)" ::: "memory");
    } else {
      asm volatile("s_waitcnt vmcnt(0)" ::: "memory");
    }
    __builtin_amdgcn_s_barrier();
    kcompute(Ab[cur], Bb[cur], wm, wn, l15, lhi, acc);
    __builtin_amdgcn_s_barrier();
    cur ^= 1;
  }

  #pragma unroll
  for (int nt=0; nt<8; ++nt){
    const int col = wn*128 + nt*16 + l15;
    const float extra = g_bias2w[b*H_ + n0 + col];
    #pragma unroll
    for (int mt=0; mt<2; ++mt){
      #pragma unroll
      for (int j=0;j<4;++j){
        const int row = wm*32 + mt*16 + lhi*4 + j;
        out[(size_t)(row0+row)*H_ + n0 + col] = acc[mt][nt][j] + extra;
      }
    }
  }
}

extern "C" void kernel_launch(void* const* d_in, const int* in_sizes, int n_in,
                              void* d_out, int out_size, void* d_ws, size_t ws_size,
                              hipStream_t stream){
  const float* hidden = (const float*)d_in[0];
  const float* head_w = (const float*)d_in[1];
  const float* head_b = (const float*)d_in[2];
  const float* embeds = (const float*)d_in[3];
  const float* w1     = (const float*)d_in[4];
  const float* b1     = (const float*)d_in[5];
  const float* w2     = (const float*)d_in[6];
  const float* b2     = (const float*)d_in[7];
  float* out = (float*)d_out;
  float* pooled = (float*)d_ws;   // B_*H_ floats, zeroed below
  (void)in_sizes; (void)n_in; (void)out_size; (void)ws_size;

  hipMemsetAsync(pooled, 0, B_*H_*sizeof(float), stream);
  cvt_pool      <<<M_TOT/64, 256, 0, stream>>>(hidden, pooled);
  routing_kernel<<<1, 512, 0, stream>>>(pooled, head_w, head_b, b2);
  transpose_cvt <<<P_*(H_/32)*(K_/32), 256, 0, stream>>>(w1, H_, K_, 0);
  transpose_cvt <<<P_*(K_/32)*(H_/32), 256, 0, stream>>>(w2, K_, H_, 1);
  bias1_kernel  <<<P_*8, 256, 0, stream>>>(embeds, w1, b1);
  l1_kernel     <<<P_*256, 256, 0, stream>>>();
  l2_kernel     <<<512, 256, 0, stream>>>(out);
}

// Round 5
// 299.979 us; speedup vs baseline: 4.0051x; 1.1295x over previous
//
#include <hip/hip_runtime.h>
#include <hip/hip_bf16.h>
#include <stdint.h>

#define B_ 8
#define S_ 2048
#define H_ 512
#define P_ 16
#define K_ 256
#define M_TOT (B_*S_)      // 16384
#define KCAT (P_*K_)       // 4096

typedef short bf8v __attribute__((ext_vector_type(8)));   // 8 x bf16 (MFMA operand)
typedef float f4v  __attribute__((ext_vector_type(4)));   // MFMA accumulator

// ---- device-global scratch (recomputed from inputs on every call) ----
__device__ __align__(16) unsigned short g_hidden[M_TOT*H_];        // bf16 [m][h]
__device__ __align__(16) unsigned short g_w1t[P_*K_*H_];           // bf16 [n=p*256+k][h]
__device__ __align__(16) unsigned short g_w2cat[H_*KCAT];          // bf16 [h][p*256+k]
__device__ __align__(16) unsigned short g_mid[(size_t)M_TOT*KCAT]; // bf16 [m][p*256+k]
__device__ float g_bias1[P_*K_];       // n-indexed flat
__device__ float g_probs[B_*P_];
__device__ float g_bias2w[B_*H_];

__device__ __forceinline__ unsigned short f2bf(float x){
  unsigned int u = __builtin_bit_cast(unsigned int, x);
  u += 0x7fffu + ((u >> 16) & 1u);              // round-to-nearest-even
  return (unsigned short)(u >> 16);
}

// exact GELU: 0.5*x*(1+erf(x/sqrt(2))), erf via A&S 7.1.26 (|err|<1.5e-7)
__device__ __forceinline__ float gelu_exact(float x){
  float z  = x * 0.70710678f;
  float az = fabsf(z);
  float t  = 1.0f / (1.0f + 0.3275911f * az);
  float poly = t*(0.254829592f + t*(-0.284496736f + t*(1.421413741f +
               t*(-1.453152027f + t*1.061405429f))));
  float e = __expf(-az*az);
  float erfv = 1.0f - poly*e;
  erfv = (z < 0.0f) ? -erfv : erfv;
  return 0.5f * x * (1.0f + erfv);
}

__device__ __forceinline__ void gll16(const unsigned short* src, unsigned short* lds){
  __builtin_amdgcn_global_load_lds(
      (const __attribute__((address_space(1))) unsigned int*)src,
      (__attribute__((address_space(3))) unsigned int*)lds,
      16, 0, 0);
}

// ---------- pre-pass: hidden fp32 -> bf16, fused with pooled-sum ----------
__global__ void cvt_pool(const float* __restrict__ hs, float* __restrict__ pooled){
  const int row0 = blockIdx.x * 64;
  const int b = row0 >> 11;
  const int tx = threadIdx.x & 127, ty = threadIdx.x >> 7;
  const float4* src = (const float4*)(hs + (size_t)row0*H_) + tx;
  ushort4* dst = (ushort4*)g_hidden + (size_t)row0*(H_/4) + tx;
  float4 s = {0.f,0.f,0.f,0.f};
  for (int r = ty; r < 64; r += 2){
    float4 v = src[(size_t)r*128];
    s.x += v.x; s.y += v.y; s.z += v.z; s.w += v.w;
    ushort4 o = {f2bf(v.x), f2bf(v.y), f2bf(v.z), f2bf(v.w)};
    dst[(size_t)r*128] = o;
  }
  __shared__ float4 red[256];
  red[threadIdx.x] = s;
  __syncthreads();
  if (ty == 0){
    float4 a = red[threadIdx.x], c = red[threadIdx.x + 128];
    atomicAdd(&pooled[b*H_ + tx*4 + 0], a.x + c.x);
    atomicAdd(&pooled[b*H_ + tx*4 + 1], a.y + c.y);
    atomicAdd(&pooled[b*H_ + tx*4 + 2], a.z + c.z);
    atomicAdd(&pooled[b*H_ + tx*4 + 3], a.w + c.w);
  }
}

// ---------- pre-pass: logits, softmax, bias2w ----------
__global__ void routing_kernel(const float* __restrict__ pooled,
                               const float* __restrict__ head_w,
                               const float* __restrict__ head_b,
                               const float* __restrict__ b2){
  __shared__ float logits[B_][P_];
  __shared__ float sprob[B_][P_];
  int w = threadIdx.x >> 6, lane = threadIdx.x & 63;
  for (int i = 0; i < 16; ++i){
    int pair = w*16 + i; int b = pair >> 4; int p = pair & 15;
    float acc = 0.0f;
    for (int h = lane; h < H_; h += 64) acc += pooled[b*H_+h]*head_w[p*H_+h];
    for (int off=32; off; off>>=1) acc += __shfl_down(acc, off);
    if (lane==0) logits[b][p] = acc * (1.0f/S_) + head_b[p];
  }
  __syncthreads();
  if (threadIdx.x < B_){
    int b = threadIdx.x;
    float mx = -1e30f;
    #pragma unroll
    for (int p=0;p<P_;++p) mx = fmaxf(mx, logits[b][p]);
    float e[P_]; float s = 0.0f;
    #pragma unroll
    for (int p=0;p<P_;++p){ e[p] = __expf(logits[b][p]-mx); s += e[p]; }
    float inv = 1.0f/s;
    #pragma unroll
    for (int p=0;p<P_;++p){ float pr = e[p]*inv; g_probs[b*P_+p] = pr; sprob[b][p] = pr; }
  }
  __syncthreads();
  for (int idx = threadIdx.x; idx < B_*H_; idx += blockDim.x){
    int b = idx >> 9, h = idx & (H_-1);
    float a = 0.0f;
    #pragma unroll
    for (int p=0;p<P_;++p) a += sprob[b][p]*b2[p*H_+h];
    g_bias2w[idx] = a;
  }
}

// ---------- pre-pass: transpose+convert weights ----------
__global__ void transpose_cvt(const float* __restrict__ in, int R, int C, int which){
  int nrt = R >> 5, nct = C >> 5;
  int p   = blockIdx.x / (nrt*nct);
  int rem = blockIdx.x % (nrt*nct);
  int rt = rem / nct, ct = rem % nct;
  int tx = threadIdx.x & 31, ty = threadIdx.x >> 5;    // 32 x 8
  __shared__ float t[32][33];
  const float* ip = in + (size_t)p*R*C + (size_t)(rt*32 + ty)*C + ct*32 + tx;
  #pragma unroll
  for (int k=0;k<4;++k) t[ty + 8*k][tx] = ip[(size_t)8*k*C];
  __syncthreads();
  if (which == 0){
    unsigned short* op = g_w1t + (size_t)p*R*C + (size_t)(ct*32 + ty)*R + rt*32 + tx;
    #pragma unroll
    for (int k=0;k<4;++k) op[(size_t)8*k*R] = f2bf(t[tx][ty + 8*k]);
  } else {
    unsigned short* op = g_w2cat + (size_t)(ct*32 + ty)*KCAT + p*K_ + rt*32 + tx;
    #pragma unroll
    for (int k=0;k<4;++k) op[(size_t)8*k*KCAT] = f2bf(t[tx][ty + 8*k]);
  }
}

// ---------- pre-pass: bias1[p][k] = embed[p]@w1[p][:,k] + b1[p][k] ----------
__global__ void bias1_kernel(const float* __restrict__ embeds,
                             const float* __restrict__ w1,
                             const float* __restrict__ b1){
  int p = blockIdx.x >> 3, kg = blockIdx.x & 7;
  int ks = threadIdx.x & 31, hs = threadIdx.x >> 5;
  int kk = kg*32 + ks;
  float acc = 0.0f;
  for (int h = hs; h < H_; h += 8)
    acc += embeds[p*H_ + h] * w1[((size_t)p*H_ + h)*K_ + kk];
  __shared__ float red[8][33];
  red[hs][ks] = acc; __syncthreads();
  if (hs==0){
    float t = 0.0f;
    #pragma unroll
    for (int i=0;i<8;++i) t += red[i][ks];
    g_bias1[p*K_ + kk] = t + b1[p*K_+kk];
  }
}

// ================= unified GEMM template (m97 structure) =================
// BM=BN=128, BK=64. 256 thr = 4 waves (2M x 2N), wave-tile 64x64, acc[4][4].
// Single-buffered LDS 32KB: stage -> sync (drains vmcnt) -> compute -> sync.
// LDS tiles [row][64k] bf16 (128B rows), XOR-swizzled: byte ^= (row&7)<<4;
// linear LDS dest + inverse-swizzled per-lane global source.

__device__ __forceinline__ void stage128(unsigned short* Ab, unsigned short* Bb,
    const unsigned short* gA, int sA, const unsigned short* gB, int sB,
    int koff, int w, int lane){
  const int l8 = lane >> 3, l7 = lane & 7;
  #pragma unroll
  for (int i=0;i<4;++i){                 // 128 rows each for A and B
    const int row = w*32 + i*8 + l8;
    const int kc = l7 ^ (row & 7);
    unsigned short* dA = Ab + (w*32+i*8)*64 + lane*8;
    unsigned short* dB = Bb + (w*32+i*8)*64 + lane*8;
    gll16(gA + (size_t)row*sA + koff + kc*8, dA);
    gll16(gB + (size_t)row*sB + koff + kc*8, dB);
  }
}

__device__ __forceinline__ void kcompute64(const unsigned short* Ab, const unsigned short* Bb,
    int wm, int wn, int l15, int lhi, f4v acc[4][4]){
  #pragma unroll
  for (int ksub=0; ksub<2; ++ksub){
    const int kb = ksub*64 + lhi*16;
    bf8v aF[4], bF[4];
    #pragma unroll
    for (int t=0; t<4; ++t){
      const int ra = wm*64 + t*16 + l15;
      aF[t] = *(const bf8v*)((const char*)Ab + ra*128 + (kb ^ ((ra&7)<<4)));
      const int rb = wn*64 + t*16 + l15;
      bF[t] = *(const bf8v*)((const char*)Bb + rb*128 + (kb ^ ((rb&7)<<4)));
    }
    #pragma unroll
    for (int mt=0; mt<4; ++mt)
      #pragma unroll
      for (int nt=0; nt<4; ++nt)
        acc[mt][nt] = __builtin_amdgcn_mfma_f32_16x16x32_bf16(aF[mt], bF[nt], acc[mt][nt], 0,0,0);
  }
}

// ---------- layer 1 as ONE wide GEMM: M=16384, N=4096 (n=p*256+k), K=512 ----------
// mid[m][n] = prob[b][n>>8] * gelu(hidden[m][:] . w1t[n][:] + bias1[n])
// grid = 4096: xcd-chunked; each XCD owns 4 n-tiles (0.5MB B, L2-resident) x all m.
__global__ __launch_bounds__(256, 3) void l1_kernel(){
  __shared__ __align__(16) unsigned short lds[2][128*64];
  const int bid = blockIdx.x;
  const int xcd = bid & 7, i = bid >> 3;          // i in [0,512)
  const int n0 = (xcd*4 + (i&3)) * 128;
  const int m0 = (i >> 2) * 128;
  const int p = n0 >> 8;
  const int b = m0 >> 11;
  const int tid = threadIdx.x, w = tid >> 6, lane = tid & 63;
  const int wm = w >> 1, wn = w & 1, l15 = lane & 15, lhi = lane >> 4;
  const unsigned short* gA = g_hidden + (size_t)m0 * H_;
  const unsigned short* gB = g_w1t + (size_t)n0 * H_;

  f4v acc[4][4];
  #pragma unroll
  for (int a=0;a<4;++a)
    #pragma unroll
    for (int c=0;c<4;++c) acc[a][c] = {0.f,0.f,0.f,0.f};

  for (int kt = 0; kt < 8; ++kt){
    stage128(lds[0], lds[1], gA, H_, gB, H_, kt*64, w, lane);
    __syncthreads();
    kcompute64(lds[0], lds[1], wm, wn, l15, lhi, acc);
    __syncthreads();
  }

  // epilogue: gelu*prob -> bf16 -> LDS [128][128] (col ^ (row&3)<<3) -> coalesced stores
  unsigned short* mlds = &lds[0][0];
  const float prob = g_probs[b*P_ + p];
  #pragma unroll
  for (int nt=0; nt<4; ++nt){
    const int col = wn*64 + nt*16 + l15;
    const float bias = g_bias1[n0 + col];
    #pragma unroll
    for (int mt=0; mt<4; ++mt){
      #pragma unroll
      for (int j=0;j<4;++j){
        const int row = wm*64 + mt*16 + lhi*4 + j;
        float v = acc[mt][nt][j] + bias;
        mlds[row*128 + (col ^ ((row&3)<<3))] = f2bf(gelu_exact(v)*prob);
      }
    }
  }
  __syncthreads();
  const int c16 = tid & 15, rr = tid >> 4;
  #pragma unroll
  for (int pass=0; pass<8; ++pass){
    const int row = pass*16 + rr;
    bf8v vv = *(const bf8v*)&mlds[row*128 + ((c16*8) ^ ((row&3)<<3))];
    *(bf8v*)&g_mid[(size_t)(m0+row)*KCAT + n0 + c16*8] = vv;
  }
}

// ---------- layer 2: out = mid @ w2cat^T + bias2w : M=16384, N=512, K=4096 ----------
// grid = 512: xcd&3 -> n-tile (1MB B L2-resident); xcd>>2 halves the m-range.
__global__ __launch_bounds__(256, 3) void l2_kernel(float* __restrict__ out){
  __shared__ __align__(16) unsigned short lds[2][128*64];
  const int bid = blockIdx.x;
  const int xcd = bid & 7, i = bid >> 3;          // i in [0,64)
  const int n0 = (xcd & 3) * 128;
  const int m0 = ((xcd >> 2)*64 + i) * 128;
  const int b = m0 >> 11;
  const int tid = threadIdx.x, w = tid >> 6, lane = tid & 63;
  const int wm = w >> 1, wn = w & 1, l15 = lane & 15, lhi = lane >> 4;
  const unsigned short* gA = g_mid + (size_t)m0 * KCAT;
  const unsigned short* gB = g_w2cat + (size_t)n0 * KCAT;

  f4v acc[4][4];
  #pragma unroll
  for (int a=0;a<4;++a)
    #pragma unroll
    for (int c=0;c<4;++c) acc[a][c] = {0.f,0.f,0.f,0.f};

  for (int kt = 0; kt < 64; ++kt){
    stage128(lds[0], lds[1], gA, KCAT, gB, KCAT, kt*64, w, lane);
    __syncthreads();
    kcompute64(lds[0], lds[1], wm, wn, l15, lhi, acc);
    __syncthreads();
  }

  #pragma unroll
  for (int nt=0; nt<4; ++nt){
    const int col = n0 + wn*64 + nt*16 + l15;
    const float extra = g_bias2w[b*H_ + col];
    #pragma unroll
    for (int mt=0; mt<4; ++mt){
      #pragma unroll
      for (int j=0;j<4;++j){
        const int row = m0 + wm*64 + mt*16 + lhi*4 + j;
        out[(size_t)row*H_ + col] = acc[mt][nt][j] + extra;
      }
    }
  }
}

extern "C" void kernel_launch(void* const* d_in, const int* in_sizes, int n_in,
                              void* d_out, int out_size, void* d_ws, size_t ws_size,
                              hipStream_t stream){
  const float* hidden = (const float*)d_in[0];
  const float* head_w = (const float*)d_in[1];
  const float* head_b = (const float*)d_in[2];
  const float* embeds = (const float*)d_in[3];
  const float* w1     = (const float*)d_in[4];
  const float* b1     = (const float*)d_in[5];
  const float* w2     = (const float*)d_in[6];
  const float* b2     = (const float*)d_in[7];
  float* out = (float*)d_out;
  float* pooled = (float*)d_ws;   // B_*H_ floats, zeroed below
  (void)in_sizes; (void)n_in; (void)out_size; (void)ws_size;

  hipMemsetAsync(pooled, 0, B_*H_*sizeof(float), stream);
  cvt_pool      <<<M_TOT/64, 256, 0, stream>>>(hidden, pooled);
  routing_kernel<<<1, 512, 0, stream>>>(pooled, head_w, head_b, b2);
  transpose_cvt <<<P_*(H_/32)*(K_/32), 256, 0, stream>>>(w1, H_, K_, 0);
  transpose_cvt <<<P_*(K_/32)*(H_/32), 256, 0, stream>>>(w2, K_, H_, 1);
  bias1_kernel  <<<P_*8, 256, 0, stream>>>(embeds, w1, b1);
  l1_kernel     <<<4096, 256, 0, stream>>>();
  l2_kernel     <<<512, 256, 0, stream>>>(out);
}